// Round 1
// baseline (547.516 us; speedup 1.0000x reference)
//
#include <hip/hip_runtime.h>
#include <math.h>

#define NPTS 262144
#define MT 64          // points per block
#define XS 328         // LDS activation row stride (bf16 elems): 320 + 8 pad

typedef __attribute__((ext_vector_type(8))) short bf16x8;
typedef __attribute__((ext_vector_type(4))) float f32x4;

__device__ __forceinline__ short f2bf(float f) {
    union { float f; unsigned u; } v; v.f = f;
    unsigned r = v.u + 0x7fffu + ((v.u >> 16) & 1u);   // RNE
    return (short)(r >> 16);
}

// ---- swizzled-weight workspace layout (offsets in bf16 elements) ----
#define OFF_IN   0
#define SZ_IN    (64*256)
#define OFF_H0   (OFF_IN + SZ_IN)
#define SZ_H     (256*256)
#define OFF_H1   (OFF_H0 + SZ_H)
#define OFF_H2   (OFF_H1 + SZ_H)
#define OFF_H3   (OFF_H2 + SZ_H)
#define OFF_H4   (OFF_H3 + SZ_H)
#define SZ_H4    (320*256)
#define OFF_H5   (OFF_H4 + SZ_H4)
#define OFF_H6   (OFF_H5 + SZ_H)
#define OFF_OUT  (OFF_H6 + SZ_H)
#define SZ_OUT   (256*320)
#define OFF_R1   (OFF_OUT + SZ_OUT)
#define SZ_R1    (288*128)
#define OFF_R2   (OFF_R1 + SZ_R1)
#define SZ_R2    (128*16)
#define WS_TOTAL (OFF_R2 + SZ_R2)   // 612352 bf16 = ~1.17 MB

// ---------------- weight prep: f32 -> bf16, MFMA-B-fragment swizzle ----------
// storage: frag tile (kt,nt): elem ((kt*nNt + nt)*64 + lane)*8 + j
//          holds W[kt*32 + (lane>>4)*8 + j][nt*16 + (lane&15)]  (0-padded)
struct PrepP { const float* W[11]; short* ws; };

__global__ __launch_bounds__(256) void prep_all(PrepP pp) {
    int i = blockIdx.x * 256 + threadIdx.x;
    if (i >= WS_TOTAL) return;
    const int offs[12] = {OFF_IN, OFF_H0, OFF_H1, OFF_H2, OFF_H3, OFF_H4,
                          OFF_H5, OFF_H6, OFF_OUT, OFF_R1, OFF_R2, WS_TOTAL};
    const int Ks[11]  = {63,256,256,256,256,319,256,256,256,283,128};
    const int Ns[11]  = {256,256,256,256,256,256,256,256,257,128,3};
    const int Nps[11] = {256,256,256,256,256,256,256,256,320,128,16};
    int seg = 0;
    while (i >= offs[seg + 1]) seg++;
    int li = i - offs[seg];
    int j = li & 7, L = (li >> 3) & 63, tile = li >> 9;
    int nNt = Nps[seg] >> 4;
    int nt = tile % nNt, kt = tile / nNt;
    int k = kt * 32 + ((L >> 4) << 3) + j;
    int n = nt * 16 + (L & 15);
    float v = (k < Ks[seg] && n < Ns[seg]) ? pp.W[seg][k * Ns[seg] + n] : 0.f;
    pp.ws[i] = f2bf(v);
}

// ---------------- fused MLP ----------------
struct Params {
    const float *pos, *dir;
    const float *b_in, *b_h0, *b_h1, *b_h2, *b_h3, *b_h4, *b_h5, *b_h6;
    const float *b_out, *b_r1, *b_r2;
    const short *w;
    float *out;
};

// MODE 0: relu -> X     MODE 1: W_out layer (features no-relu -> X, density -> gmem)
template<int NKT, int NTW, int MODE>
__device__ __forceinline__ void layer(const short* __restrict__ Wsw,
                                      const float* __restrict__ bias,
                                      int nNt, int Nbias, short* X,
                                      float* dout, int p0, int wave, int lane) {
    const int l15 = lane & 15, quad = lane >> 4;
    f32x4 acc[4][NTW];
#pragma unroll
    for (int s = 0; s < 4; s++)
#pragma unroll
        for (int t = 0; t < NTW; t++) acc[s][t] = (f32x4){0.f, 0.f, 0.f, 0.f};
    __syncthreads();                      // X (this layer's input) is ready
    const short* xb = X + l15 * XS + quad * 8;
    for (int kt = 0; kt < NKT; ++kt) {
        bf16x8 a[4];
#pragma unroll
        for (int s = 0; s < 4; s++)
            a[s] = *(const bf16x8*)(xb + s * 16 * XS + kt * 32);
#pragma unroll
        for (int t = 0; t < NTW; t++) {
            const int nt = wave * NTW + t;
            bf16x8 b = *(const bf16x8*)(Wsw + (size_t)((kt * nNt + nt) * 64 + lane) * 8);
#pragma unroll
            for (int s = 0; s < 4; s++)
                acc[s][t] = __builtin_amdgcn_mfma_f32_16x16x32_bf16(a[s], b, acc[s][t], 0, 0, 0);
        }
    }
    __syncthreads();                      // all reads of X done; safe to overwrite
#pragma unroll
    for (int t = 0; t < NTW; t++) {
        const int n = (wave * NTW + t) * 16 + l15;
        const float bv = (n < Nbias) ? bias[n] : 0.f;
#pragma unroll
        for (int s = 0; s < 4; s++)
#pragma unroll
            for (int r = 0; r < 4; r++) {
                const int m = s * 16 + quad * 4 + r;   // C layout: row=quad*4+reg, col=l15
                float v = acc[s][t][r] + bv;
                if (MODE == 0) {
                    X[m * XS + n] = f2bf(fmaxf(v, 0.f));
                } else {
                    if (n < 256)       X[m * XS + n] = f2bf(v);           // features, NO relu
                    else if (n == 256) dout[3 * NPTS + p0 + m] = fmaxf(v, 0.f);  // density
                }
            }
    }
}

__global__ __launch_bounds__(256) void nerf_fused(Params P) {
    __shared__ __align__(16) short X[MT * XS];
    __shared__ __align__(16) short DE[MT * 32];
    const int tid = threadIdx.x;
    const int wave = tid >> 6, lane = tid & 63;
    const int p0 = blockIdx.x * MT;

    // ---- positional encodings ----
    // pe (63 dims + pad) -> X cols 0..63 (input-layer operand) AND cols 256..319 (h4 skip)
    for (int i = tid; i < MT * 64; i += 256) {
        const int pt = i >> 6, d = i & 63;
        float v = 0.f;
        if (d < 3) v = P.pos[(p0 + pt) * 3 + d];
        else if (d < 63) {
            const int e = d - 3, f = e / 6, r = e % 6;
            const float x = P.pos[(p0 + pt) * 3 + (r % 3)];
            const float xf = x * (float)(1 << f);
            v = (r < 3) ? sinf(xf) : cosf(xf);
        }
        const short bv = f2bf(v);
        X[pt * XS + d] = bv;
        X[pt * XS + 256 + d] = bv;
    }
    // de (27 dims + pad) -> DE
    for (int i = tid; i < MT * 32; i += 256) {
        const int pt = i >> 5, d = i & 31;
        float v = 0.f;
        if (d < 3) v = P.dir[(p0 + pt) * 3 + d];
        else if (d < 27) {
            const int e = d - 3, f = e / 6, r = e % 6;
            const float x = P.dir[(p0 + pt) * 3 + (r % 3)];
            const float xf = x * (float)(1 << f);
            v = (r < 3) ? sinf(xf) : cosf(xf);
        }
        DE[i] = f2bf(v);
    }

    layer<2, 4, 0>(P.w + OFF_IN, P.b_in, 16, 256, X, P.out, p0, wave, lane);
    layer<8, 4, 0>(P.w + OFF_H0, P.b_h0, 16, 256, X, P.out, p0, wave, lane);
    layer<8, 4, 0>(P.w + OFF_H1, P.b_h1, 16, 256, X, P.out, p0, wave, lane);
    layer<8, 4, 0>(P.w + OFF_H2, P.b_h2, 16, 256, X, P.out, p0, wave, lane);
    layer<8, 4, 0>(P.w + OFF_H3, P.b_h3, 16, 256, X, P.out, p0, wave, lane);
    layer<10, 4, 0>(P.w + OFF_H4, P.b_h4, 16, 256, X, P.out, p0, wave, lane); // concat(h,pe)
    layer<8, 4, 0>(P.w + OFF_H5, P.b_h5, 16, 256, X, P.out, p0, wave, lane);
    layer<8, 4, 0>(P.w + OFF_H6, P.b_h6, 16, 256, X, P.out, p0, wave, lane);
    layer<8, 5, 1>(P.w + OFF_OUT, P.b_out, 20, 257, X, P.out, p0, wave, lane); // features+density

    // splice de into cols 256..287 (pe no longer needed) -> rgb_in = [features | de]
    for (int i = tid; i < MT * 32; i += 256) {
        const int pt = i >> 5, d = i & 31;
        X[pt * XS + 256 + d] = DE[i];
    }

    layer<9, 2, 0>(P.w + OFF_R1, P.b_r1, 8, 128, X, P.out, p0, wave, lane);

    // ---- r2 (128 -> 3) + sigmoid; each wave handles one 16-point strip ----
    __syncthreads();
    {
        const int l15 = lane & 15, quad = lane >> 4;
        f32x4 acc = (f32x4){0.f, 0.f, 0.f, 0.f};
        const short* xb = X + (wave * 16 + l15) * XS + quad * 8;
#pragma unroll
        for (int kt = 0; kt < 4; ++kt) {
            bf16x8 a = *(const bf16x8*)(xb + kt * 32);
            bf16x8 b = *(const bf16x8*)(P.w + OFF_R2 + (size_t)(kt * 64 + lane) * 8);
            acc = __builtin_amdgcn_mfma_f32_16x16x32_bf16(a, b, acc, 0, 0, 0);
        }
        if (l15 < 3) {
            const float bv = P.b_r2[l15];
#pragma unroll
            for (int r = 0; r < 4; r++) {
                const int m = wave * 16 + quad * 4 + r;
                const float v = acc[r] + bv;
                P.out[(size_t)(p0 + m) * 3 + l15] = 1.f / (1.f + expf(-v));
            }
        }
    }
}

extern "C" void kernel_launch(void* const* d_in, const int* in_sizes, int n_in,
                              void* d_out, int out_size, void* d_ws, size_t ws_size,
                              hipStream_t stream) {
    short* ws = (short*)d_ws;

    PrepP pp;
    pp.W[0]  = (const float*)d_in[2];   // W_in
    pp.W[1]  = (const float*)d_in[4];   // W_h0
    pp.W[2]  = (const float*)d_in[6];   // W_h1
    pp.W[3]  = (const float*)d_in[8];   // W_h2
    pp.W[4]  = (const float*)d_in[10];  // W_h3
    pp.W[5]  = (const float*)d_in[12];  // W_h4
    pp.W[6]  = (const float*)d_in[14];  // W_h5
    pp.W[7]  = (const float*)d_in[16];  // W_h6
    pp.W[8]  = (const float*)d_in[18];  // W_out
    pp.W[9]  = (const float*)d_in[20];  // W_r1
    pp.W[10] = (const float*)d_in[22];  // W_r2
    pp.ws = ws;
    hipLaunchKernelGGL(prep_all, dim3((WS_TOTAL + 255) / 256), dim3(256), 0, stream, pp);

    Params P;
    P.pos  = (const float*)d_in[0];
    P.dir  = (const float*)d_in[1];
    P.b_in = (const float*)d_in[3];
    P.b_h0 = (const float*)d_in[5];
    P.b_h1 = (const float*)d_in[7];
    P.b_h2 = (const float*)d_in[9];
    P.b_h3 = (const float*)d_in[11];
    P.b_h4 = (const float*)d_in[13];
    P.b_h5 = (const float*)d_in[15];
    P.b_h6 = (const float*)d_in[17];
    P.b_out = (const float*)d_in[19];
    P.b_r1 = (const float*)d_in[21];
    P.b_r2 = (const float*)d_in[23];
    P.w = ws;
    P.out = (float*)d_out;
    hipLaunchKernelGGL(nerf_fused, dim3(NPTS / MT), dim3(256), 0, stream, P);
}

// Round 2
// 441.934 us; speedup vs baseline: 1.2389x; 1.2389x over previous
//
#include <hip/hip_runtime.h>
#include <math.h>

#define NPTS 262144
#define MT 64          // points per block
#define XS 328         // LDS activation row stride (bf16 elems): 320 + 8 pad
#define NWAVE 8        // waves per block

typedef __attribute__((ext_vector_type(8))) short bf16x8;
typedef __attribute__((ext_vector_type(4))) float f32x4;
typedef __attribute__((ext_vector_type(2))) unsigned int u32x2;

__device__ __forceinline__ short f2bf(float f) {
    union { float f; unsigned u; } v; v.f = f;
    unsigned r = v.u + 0x7fffu + ((v.u >> 16) & 1u);   // RNE
    return (short)(r >> 16);
}
__device__ __forceinline__ unsigned pk2(float a, float b) {
    return ((unsigned)(unsigned short)f2bf(a)) |
           ((unsigned)(unsigned short)f2bf(b) << 16);
}

// ---- swizzled-weight workspace layout (offsets in bf16 elements) ----
#define OFF_IN   0
#define SZ_IN    (64*256)
#define OFF_H0   (OFF_IN + SZ_IN)
#define SZ_H     (256*256)
#define OFF_H1   (OFF_H0 + SZ_H)
#define OFF_H2   (OFF_H1 + SZ_H)
#define OFF_H3   (OFF_H2 + SZ_H)
#define OFF_H4   (OFF_H3 + SZ_H)
#define SZ_H4    (320*256)
#define OFF_H5   (OFF_H4 + SZ_H4)
#define OFF_H6   (OFF_H5 + SZ_H)
#define OFF_OUT  (OFF_H6 + SZ_H)
#define SZ_OUT   (256*272)          // N padded to 272 = 17 tiles (density tile = 16)
#define OFF_R1   (OFF_OUT + SZ_OUT)
#define SZ_R1    (288*128)
#define OFF_R2   (OFF_R1 + SZ_R1)
#define SZ_R2    (128*16)
#define WS_TOTAL (OFF_R2 + SZ_R2)

// ---------------- weight prep: f32 -> bf16, MFMA fragment swizzle ----------
// frag tile (kt,nt): elem ((kt*nNt + nt)*64 + lane)*8 + j
//   holds W[kt*32 + (lane>>4)*8 + j][nt*16 + (lane&15)]  (0-padded)
// (same bytes serve as B-frag [k][n] or, transposed, as A-frag of W^T)
struct PrepP { const float* W[11]; short* ws; };

__global__ __launch_bounds__(256) void prep_all(PrepP pp) {
    int i = blockIdx.x * 256 + threadIdx.x;
    if (i >= WS_TOTAL) return;
    const int offs[12] = {OFF_IN, OFF_H0, OFF_H1, OFF_H2, OFF_H3, OFF_H4,
                          OFF_H5, OFF_H6, OFF_OUT, OFF_R1, OFF_R2, WS_TOTAL};
    const int Ks[11]  = {63,256,256,256,256,319,256,256,256,283,128};
    const int Ns[11]  = {256,256,256,256,256,256,256,256,257,128,3};
    const int Nps[11] = {256,256,256,256,256,256,256,256,272,128,16};
    int seg = 0;
    while (i >= offs[seg + 1]) seg++;
    int li = i - offs[seg];
    int j = li & 7, L = (li >> 3) & 63, tile = li >> 9;
    int nNt = Nps[seg] >> 4;
    int nt = tile % nNt, kt = tile / nNt;
    int k = kt * 32 + ((L >> 4) << 3) + j;
    int n = nt * 16 + (L & 15);
    float v = (k < Ks[seg] && n < Ns[seg]) ? pp.W[seg][k * Ns[seg] + n] : 0.f;
    pp.ws[i] = f2bf(v);
}

// ---------------- fused MLP ----------------
struct Params {
    const float *pos, *dir;
    const float *b_in, *b_h0, *b_h1, *b_h2, *b_h3, *b_h4, *b_h5, *b_h6;
    const float *b_out, *b_r1, *b_r2;
    const short *w;
    float *out;
};

// Transposed MFMA: A = W^T (M-dim = output feature n), B = X^T (N-dim = point m).
// C layout: row(quad*4+r) = n-in-tile, col(l15) = m-in-tile -> thread holds 4
// consecutive n for one point -> packed b64 LDS store.
// NKT = K-tiles, NS = n-tiles per wave, NT = total n-tiles (addressing stride
// AND validity bound), MODE 0: relu->X; MODE 1: out layer (features no-relu ->X,
// density tile nt==16 -> gmem).
template<int NKT, int NS, int NT, int MODE>
__device__ __forceinline__ void layerT(const short* __restrict__ Wsw,
                                       const float* __restrict__ bias,
                                       short* X, float* dout, int p0,
                                       int wave, int lane) {
    const int l15 = lane & 15, quad = lane >> 4;
    f32x4 acc[NS][4];
#pragma unroll
    for (int s = 0; s < NS; s++)
#pragma unroll
        for (int t = 0; t < 4; t++) acc[s][t] = (f32x4){0.f, 0.f, 0.f, 0.f};
    __syncthreads();                      // X (this layer's input) is ready
    const short* xb = X + l15 * XS + quad * 8;
    for (int kt = 0; kt < NKT; ++kt) {
        bf16x8 b[4];
#pragma unroll
        for (int t = 0; t < 4; t++)
            b[t] = *(const bf16x8*)(xb + t * 16 * XS + kt * 32);
#pragma unroll
        for (int s = 0; s < NS; s++) {
            const int nt = s * NWAVE + wave;
            if (NS * NWAVE > NT && nt >= NT) break;
            bf16x8 a = *(const bf16x8*)(Wsw + (size_t)((kt * NT + nt) * 64 + lane) * 8);
#pragma unroll
            for (int t = 0; t < 4; t++)
                acc[s][t] = __builtin_amdgcn_mfma_f32_16x16x32_bf16(a, b[t], acc[s][t], 0, 0, 0);
        }
    }
    __syncthreads();                      // all reads of X done; safe to overwrite
#pragma unroll
    for (int s = 0; s < NS; s++) {
        const int nt = s * NWAVE + wave;
        if (NS * NWAVE > NT && nt >= NT) break;
        if (MODE == 1 && nt == 16) {      // density tile: only n==256 is real
            if (quad == 0) {
                const float bv = bias[256];
#pragma unroll
                for (int t = 0; t < 4; t++) {
                    const int m = t * 16 + l15;
                    dout[3 * NPTS + p0 + m] = fmaxf(acc[s][t][0] + bv, 0.f);
                }
            }
        } else {
            const int n0 = nt * 16 + quad * 4;
            const f32x4 bv = *(const f32x4*)(bias + n0);
#pragma unroll
            for (int t = 0; t < 4; t++) {
                const int m = t * 16 + l15;
                float v0 = acc[s][t][0] + bv[0];
                float v1 = acc[s][t][1] + bv[1];
                float v2 = acc[s][t][2] + bv[2];
                float v3 = acc[s][t][3] + bv[3];
                if (MODE == 0) {
                    v0 = fmaxf(v0, 0.f); v1 = fmaxf(v1, 0.f);
                    v2 = fmaxf(v2, 0.f); v3 = fmaxf(v3, 0.f);
                }
                u32x2 w; w[0] = pk2(v0, v1); w[1] = pk2(v2, v3);
                *(u32x2*)(X + m * XS + n0) = w;
            }
        }
    }
}

__global__ __launch_bounds__(512, 6) void nerf_fused(Params P) {
    __shared__ __align__(16) short X[MT * XS];
    __shared__ __align__(16) short DE[MT * 32];
    const int tid = threadIdx.x;
    const int wave = tid >> 6, lane = tid & 63;
    const int p0 = blockIdx.x * MT;

    // ---- positional encodings ----
    // pe (63 dims + pad) -> X cols 0..63 (input layer) AND cols 256..319 (h4 skip)
    for (int i = tid; i < MT * 64; i += 512) {
        const int pt = i >> 6, d = i & 63;
        float v = 0.f;
        if (d < 3) v = P.pos[(p0 + pt) * 3 + d];
        else if (d < 63) {
            const int e = d - 3, f = e / 6, r = e % 6;
            const float x = P.pos[(p0 + pt) * 3 + (r % 3)];
            const float xf = x * (float)(1 << f);
            v = (r < 3) ? sinf(xf) : cosf(xf);
        }
        const short bv = f2bf(v);
        X[pt * XS + d] = bv;
        X[pt * XS + 256 + d] = bv;
    }
    // de (27 dims + pad) -> DE
    for (int i = tid; i < MT * 32; i += 512) {
        const int pt = i >> 5, d = i & 31;
        float v = 0.f;
        if (d < 3) v = P.dir[(p0 + pt) * 3 + d];
        else if (d < 27) {
            const int e = d - 3, f = e / 6, r = e % 6;
            const float x = P.dir[(p0 + pt) * 3 + (r % 3)];
            const float xf = x * (float)(1 << f);
            v = (r < 3) ? sinf(xf) : cosf(xf);
        }
        DE[i] = f2bf(v);
    }

    layerT<2, 2, 16, 0>(P.w + OFF_IN, P.b_in, X, P.out, p0, wave, lane);
    layerT<8, 2, 16, 0>(P.w + OFF_H0, P.b_h0, X, P.out, p0, wave, lane);
    layerT<8, 2, 16, 0>(P.w + OFF_H1, P.b_h1, X, P.out, p0, wave, lane);
    layerT<8, 2, 16, 0>(P.w + OFF_H2, P.b_h2, X, P.out, p0, wave, lane);
    layerT<8, 2, 16, 0>(P.w + OFF_H3, P.b_h3, X, P.out, p0, wave, lane);
    layerT<10, 2, 16, 0>(P.w + OFF_H4, P.b_h4, X, P.out, p0, wave, lane); // concat(h,pe)
    layerT<8, 2, 16, 0>(P.w + OFF_H5, P.b_h5, X, P.out, p0, wave, lane);
    layerT<8, 2, 16, 0>(P.w + OFF_H6, P.b_h6, X, P.out, p0, wave, lane);
    layerT<8, 3, 17, 1>(P.w + OFF_OUT, P.b_out, X, P.out, p0, wave, lane); // features+density

    // splice de into cols 256..287 (pe no longer needed) -> rgb_in = [features | de]
    __syncthreads();
    for (int i = tid; i < MT * 32; i += 512) {
        const int pt = i >> 5, d = i & 31;
        X[pt * XS + 256 + d] = DE[i];
    }

    layerT<9, 1, 8, 0>(P.w + OFF_R1, P.b_r1, X, P.out, p0, wave, lane);

    // ---- r2 (128 -> 3) + sigmoid; waves 0..3 each take one 16-point tile ----
    __syncthreads();
    if (wave < 4) {
        const int l15 = lane & 15, quad = lane >> 4;
        f32x4 acc = (f32x4){0.f, 0.f, 0.f, 0.f};
        const short* xb = X + (wave * 16 + l15) * XS + quad * 8;
#pragma unroll
        for (int kt = 0; kt < 4; ++kt) {
            bf16x8 b = *(const bf16x8*)(xb + kt * 32);
            bf16x8 a = *(const bf16x8*)(P.w + OFF_R2 + (size_t)(kt * 64 + lane) * 8);
            acc = __builtin_amdgcn_mfma_f32_16x16x32_bf16(a, b, acc, 0, 0, 0);
        }
        if (quad == 0) {                       // rows r = n = rgb channel
#pragma unroll
            for (int r = 0; r < 3; r++) {
                const float v = acc[r] + P.b_r2[r];
                P.out[(size_t)(p0 + wave * 16 + l15) * 3 + r] = 1.f / (1.f + expf(-v));
            }
        }
    }
}

extern "C" void kernel_launch(void* const* d_in, const int* in_sizes, int n_in,
                              void* d_out, int out_size, void* d_ws, size_t ws_size,
                              hipStream_t stream) {
    short* ws = (short*)d_ws;

    PrepP pp;
    pp.W[0]  = (const float*)d_in[2];   // W_in
    pp.W[1]  = (const float*)d_in[4];   // W_h0
    pp.W[2]  = (const float*)d_in[6];   // W_h1
    pp.W[3]  = (const float*)d_in[8];   // W_h2
    pp.W[4]  = (const float*)d_in[10];  // W_h3
    pp.W[5]  = (const float*)d_in[12];  // W_h4
    pp.W[6]  = (const float*)d_in[14];  // W_h5
    pp.W[7]  = (const float*)d_in[16];  // W_h6
    pp.W[8]  = (const float*)d_in[18];  // W_out
    pp.W[9]  = (const float*)d_in[20];  // W_r1
    pp.W[10] = (const float*)d_in[22];  // W_r2
    pp.ws = ws;
    hipLaunchKernelGGL(prep_all, dim3((WS_TOTAL + 255) / 256), dim3(256), 0, stream, pp);

    Params P;
    P.pos  = (const float*)d_in[0];
    P.dir  = (const float*)d_in[1];
    P.b_in = (const float*)d_in[3];
    P.b_h0 = (const float*)d_in[5];
    P.b_h1 = (const float*)d_in[7];
    P.b_h2 = (const float*)d_in[9];
    P.b_h3 = (const float*)d_in[11];
    P.b_h4 = (const float*)d_in[13];
    P.b_h5 = (const float*)d_in[15];
    P.b_h6 = (const float*)d_in[17];
    P.b_out = (const float*)d_in[19];
    P.b_r1 = (const float*)d_in[21];
    P.b_r2 = (const float*)d_in[23];
    P.w = ws;
    P.out = (float*)d_out;
    hipLaunchKernelGGL(nerf_fused, dim3(NPTS / MT), dim3(512), 0, stream, P);
}